// Round 1
// baseline (1442.149 us; speedup 1.0000x reference)
//
#include <hip/hip_runtime.h>
#include <math.h>

constexpr int DIM   = 128;
constexpr int KC    = 1024;
constexpr int NROWS = 65536;                 // 16384*512/128
constexpr int XEL   = NROWS * DIM;           // 8388608

// output layout (floats)
constexpr int OUT_Z     = 0;
constexpr int OUT_DIFF  = XEL;               // 8388608
constexpr int OUT_CODES = XEL + 1;           // 8388609
constexpr int OUT_PPL   = XEL + 1 + NROWS;   // 8454145

// ws layout (4-byte units)
constexpr int WS_IDX  = 0;                   // int[NROWS]
constexpr int WS_FLAG = NROWS;               // int[NROWS]
constexpr int WS_CNT  = 2 * NROWS;           // int (zeroed)
constexpr int WS_CNTS = 2 * NROWS + 1;       // float[KC] (zeroed)
constexpr int WS_DACC = 2 * NROWS + 1 + KC;  // float (zeroed)
constexpr int WS_HN   = 2 * NROWS + 2 + KC;  // float[KC]

constexpr float GAP_THR = 0.02f;             // fp32 score error bound ~2e-4; 100x margin

// ---- half squared norms of codes, fp64-accurate then rounded once ----
__global__ void k_halfnorm(const float* __restrict__ emb, float* __restrict__ hn) {
    int k = blockIdx.x * blockDim.x + threadIdx.x;
    if (k >= KC) return;
    const float* e = emb + (size_t)k * DIM;
    double s = 0.0;
    for (int j = 0; j < DIM; ++j) { double v = e[j]; s = fma(v, v, s); }
    hn[k] = (float)(0.5 * s);
}

// ---- main: per-thread row, argmax of (x.e - 0.5||e||^2), track top-2 ----
__global__ __launch_bounds__(256, 1) void k_argmin(
        const float* __restrict__ x, const float* __restrict__ emb,
        const float* __restrict__ hn, int* __restrict__ idx_out,
        int* __restrict__ flag_cnt, int* __restrict__ flagged) {
    int row = blockIdx.x * 256 + threadIdx.x;
    float xr[DIM];
    const float4* xp = (const float4*)(x + (size_t)row * DIM);
    #pragma unroll
    for (int j = 0; j < DIM / 4; ++j) {
        float4 v = xp[j];
        xr[4*j+0] = v.x; xr[4*j+1] = v.y; xr[4*j+2] = v.z; xr[4*j+3] = v.w;
    }
    float m1 = -1e30f, m2 = -1e30f;
    int best = 0;
    #pragma unroll 2
    for (int k = 0; k < KC; ++k) {
        const float* ek = emb + k * DIM;       // wave-uniform -> s_loads
        float hnk = hn[k];
        float s0 = 0.f, s1 = 0.f, s2 = 0.f, s3 = 0.f;
        #pragma unroll
        for (int j = 0; j < DIM; j += 4) {
            s0 = fmaf(ek[j+0], xr[j+0], s0);
            s1 = fmaf(ek[j+1], xr[j+1], s1);
            s2 = fmaf(ek[j+2], xr[j+2], s2);
            s3 = fmaf(ek[j+3], xr[j+3], s3);
        }
        float s = ((s0 + s1) + (s2 + s3)) - hnk;
        if (s > m1) { m2 = m1; m1 = s; best = k; }
        else if (s > m2) { m2 = s; }
    }
    idx_out[row] = best;
    if (m1 - m2 < GAP_THR) {                    // near-tie: exact recheck later
        int p = atomicAdd(flag_cnt, 1);
        flagged[p] = row;
    }
}

// ---- exact fp64 recheck of near-tie rows (one wave per row) ----
__global__ void k_recheck(const float* __restrict__ x, const float* __restrict__ emb,
                          int* __restrict__ idx_out, const int* __restrict__ flag_cnt,
                          const int* __restrict__ flagged) {
    int gtid = blockIdx.x * blockDim.x + threadIdx.x;
    int wave = gtid >> 6;
    int lane = threadIdx.x & 63;
    int nw = (gridDim.x * blockDim.x) >> 6;
    int cnt = flag_cnt[0];
    for (int f = wave; f < cnt; f += nw) {
        int row = flagged[f];
        const float* xr = x + (size_t)row * DIM;
        double bestv = -1e300;
        int bestk = KC;
        for (int k = lane; k < KC; k += 64) {
            const float* ek = emb + (size_t)k * DIM;
            double s = 0.0, n2 = 0.0;
            for (int j = 0; j < DIM; ++j) {
                double e = ek[j], xv = xr[j];
                s = fma(e, xv, s);
                n2 = fma(e, e, n2);
            }
            s -= 0.5 * n2;
            if (s > bestv) { bestv = s; bestk = k; }
        }
        // wave argmax, tie -> smallest index (argmin-first semantics)
        for (int off = 32; off; off >>= 1) {
            double ov = __shfl_down(bestv, off);
            int oi = __shfl_down(bestk, off);
            if (ov > bestv || (ov == bestv && oi < bestk)) { bestv = ov; bestk = oi; }
        }
        bestk = __shfl(bestk, 0);
        if (lane == 0) idx_out[row] = bestk;
    }
}

// ---- z, codes, diff partials, histogram ----
__global__ void k_output(const float* __restrict__ x, const float* __restrict__ emb,
                         const int* __restrict__ idx, float* __restrict__ out,
                         float* __restrict__ counts, float* __restrict__ dacc) {
    int t = blockIdx.x * blockDim.x + threadIdx.x;
    int e0 = t * 4;
    int row = e0 >> 7;
    int col = e0 & (DIM - 1);
    int k = idx[row];
    float4 xv = *(const float4*)(x + e0);
    float4 qv = *(const float4*)(emb + (size_t)k * DIM + col);
    float dx = qv.x - xv.x, dy = qv.y - xv.y, dz = qv.z - xv.z, dw = qv.w - xv.w;
    float4 z;
    z.x = xv.x + dx; z.y = xv.y + dy; z.z = xv.z + dz; z.w = xv.w + dw;
    *(float4*)(out + OUT_Z + e0) = z;
    float d = dx*dx + dy*dy + dz*dz + dw*dw;
    // wave reduce then block reduce -> one atomic per block
    for (int off = 32; off; off >>= 1) d += __shfl_down(d, off);
    __shared__ float red[4];
    int lane = threadIdx.x & 63, w = threadIdx.x >> 6;
    if (lane == 0) red[w] = d;
    __syncthreads();
    if (threadIdx.x == 0) atomicAdd(dacc, (red[0] + red[1]) + (red[2] + red[3]));
    if (col == 0) {
        out[OUT_CODES + row] = (float)k;
        atomicAdd(&counts[k], 1.0f);
    }
}

// ---- diff mean + perplexity ----
__global__ void k_final(const float* __restrict__ counts, const float* __restrict__ dacc,
                        float* __restrict__ out) {
    __shared__ double sh[256];
    double local = 0.0;
    for (int k = threadIdx.x; k < KC; k += 256) {
        double p = (double)counts[k] * (1.0 / (double)NROWS);
        local += p * log(p + 1e-5);
    }
    sh[threadIdx.x] = local;
    __syncthreads();
    for (int s = 128; s; s >>= 1) {
        if (threadIdx.x < s) sh[threadIdx.x] += sh[threadIdx.x + s];
        __syncthreads();
    }
    if (threadIdx.x == 0) {
        out[OUT_DIFF] = dacc[0] * (1.0f / (float)XEL);
        out[OUT_PPL]  = (float)(-sh[0]);
    }
}

extern "C" void kernel_launch(void* const* d_in, const int* in_sizes, int n_in,
                              void* d_out, int out_size, void* d_ws, size_t ws_size,
                              hipStream_t stream) {
    const float* x   = (const float*)d_in[0];
    const float* emb = (const float*)d_in[1];
    float* out = (float*)d_out;
    int*   wi  = (int*)d_ws;
    float* wf  = (float*)d_ws;

    // zero: flag counter, histogram, diff accumulator (contiguous)
    hipMemsetAsync((char*)d_ws + (size_t)WS_CNT * 4, 0, (size_t)(2 + KC) * 4, stream);

    k_halfnorm<<<(KC + 255) / 256, 256, 0, stream>>>(emb, wf + WS_HN);
    k_argmin<<<NROWS / 256, 256, 0, stream>>>(x, emb, wf + WS_HN,
                                              wi + WS_IDX, wi + WS_CNT, wi + WS_FLAG);
    k_recheck<<<64, 256, 0, stream>>>(x, emb, wi + WS_IDX, wi + WS_CNT, wi + WS_FLAG);
    k_output<<<(XEL / 4) / 256, 256, 0, stream>>>(x, emb, wi + WS_IDX, out,
                                                  wf + WS_CNTS, wf + WS_DACC);
    k_final<<<1, 256, 0, stream>>>(wf + WS_CNTS, wf + WS_DACC, out);
}

// Round 2
// 277.635 us; speedup vs baseline: 5.1944x; 5.1944x over previous
//
#include <hip/hip_runtime.h>
#include <math.h>

constexpr int DIM   = 128;
constexpr int KC    = 1024;
constexpr int NROWS = 65536;                 // 16384*512/128
constexpr int XEL   = NROWS * DIM;           // 8388608

// output layout (floats)
constexpr int OUT_Z     = 0;
constexpr int OUT_DIFF  = XEL;               // 8388608
constexpr int OUT_CODES = XEL + 1;           // 8388609
constexpr int OUT_PPL   = XEL + 1 + NROWS;   // 8454145

// ws layout (4-byte units)
constexpr int WS_IDX  = 0;                   // int[NROWS]
constexpr int WS_FLAG = NROWS;               // int[NROWS]
constexpr int WS_CNT  = 2 * NROWS;           // int (zeroed)
constexpr int WS_CNTS = 2 * NROWS + 1;       // float[KC] (zeroed)
constexpr int WS_DACC = 2 * NROWS + 1 + KC;  // float (zeroed)
constexpr int WS_HN   = 2 * NROWS + 2 + KC;  // float[KC]
constexpr int WS_EH   = WS_HN + KC;          // ushort[KC*DIM] = 65536 words
constexpr int WS_EL   = WS_EH + (KC * DIM / 2);

constexpr float GAP_THR = 0.02f;             // score error ~5e-4; 40x margin

typedef __bf16 bf16x8 __attribute__((ext_vector_type(8)));
typedef unsigned short us8 __attribute__((ext_vector_type(8)));
typedef float f32x4 __attribute__((ext_vector_type(4)));

__device__ inline unsigned short f2bf(float f) {
    unsigned u = __builtin_bit_cast(unsigned, f);
    return (unsigned short)((u + 0x7FFFu + ((u >> 16) & 1u)) >> 16);
}
__device__ inline float bf2f(unsigned short h) {
    unsigned u = ((unsigned)h) << 16;
    return __builtin_bit_cast(float, u);
}

// ---- emb -> bf16 hi/lo splits ----
__global__ void k_prep_e(const float* __restrict__ emb, unsigned short* __restrict__ eh,
                         unsigned short* __restrict__ el) {
    int t = blockIdx.x * blockDim.x + threadIdx.x;
    int e0 = t * 4;
    float4 v = *(const float4*)(emb + e0);
    float vv[4] = {v.x, v.y, v.z, v.w};
    ushort4 h, lo;
    unsigned short* hp = &h.x; unsigned short* lp = &lo.x;
    #pragma unroll
    for (int j = 0; j < 4; ++j) {
        unsigned short hh = f2bf(vv[j]);
        hp[j] = hh;
        lp[j] = f2bf(vv[j] - bf2f(hh));
    }
    *(ushort4*)(eh + e0) = h;
    *(ushort4*)(el + e0) = lo;
}

// ---- half squared norms of codes, fp64-accurate then rounded once ----
__global__ void k_halfnorm(const float* __restrict__ emb, float* __restrict__ hn) {
    int k = blockIdx.x * blockDim.x + threadIdx.x;
    if (k >= KC) return;
    const float* e = emb + (size_t)k * DIM;
    double s = 0.0;
    for (int j = 0; j < DIM; ++j) { double v = e[j]; s = fma(v, v, s); }
    hn[k] = (float)(0.5 * s);
}

// ---- main: MFMA split-bf16 scores, per-row top-2 + argmax ----
__global__ __launch_bounds__(256) void k_argmin(
        const float* __restrict__ x,
        const unsigned short* __restrict__ eh, const unsigned short* __restrict__ el,
        const float* __restrict__ hn, int* __restrict__ idx_out,
        int* __restrict__ flag_cnt, int* __restrict__ flagged) {
    __shared__ unsigned short lds[8192];      // 16 KB: 16 chunks of 1 KB
    const int tid = threadIdx.x;
    const int l = tid & 63, w = tid >> 6;
    const int lr = l & 15, lg = l >> 4;       // row/col-select, k-group
    const int r0 = blockIdx.x * 128 + w * 32;

    // ---- A fragments: 32 rows, fp32 -> (hi,lo) bf16, kept in registers ----
    bf16x8 ah[2][4], al[2][4];
    #pragma unroll
    for (int i = 0; i < 2; ++i) {
        const float* xr = x + (size_t)(r0 + i * 16 + lr) * DIM + lg * 8;
        #pragma unroll
        for (int kt = 0; kt < 4; ++kt) {
            float4 v0 = *(const float4*)(xr + kt * 32);
            float4 v1 = *(const float4*)(xr + kt * 32 + 4);
            float vv[8] = {v0.x, v0.y, v0.z, v0.w, v1.x, v1.y, v1.z, v1.w};
            us8 h, lo;
            #pragma unroll
            for (int e = 0; e < 8; ++e) {
                unsigned short hh = f2bf(vv[e]);
                h[e] = hh;
                lo[e] = f2bf(vv[e] - bf2f(hh));
            }
            ah[i][kt] = __builtin_bit_cast(bf16x8, h);
            al[i][kt] = __builtin_bit_cast(bf16x8, lo);
        }
    }

    // staging source pointers: chunk q = w*4+i; split=q>>3, cf=(q>>2)&1, kt=q&3
    const unsigned short* esrc[4];
    #pragma unroll
    for (int i = 0; i < 4; ++i) {
        int q = w * 4 + i;
        const unsigned short* base = (q >> 3) ? el : eh;
        esrc[i] = base + (((q >> 2) & 1) * 16 + lr) * DIM + (q & 3) * 32 + lg * 8;
    }
    us8 st[4];
    #pragma unroll
    for (int i = 0; i < 4; ++i) st[i] = *(const us8*)(esrc[i]);

    float m1[2][4], m2[2][4]; int bi[2][4];
    #pragma unroll
    for (int i = 0; i < 2; ++i)
        #pragma unroll
        for (int rg = 0; rg < 4; ++rg) { m1[i][rg] = -3e38f; m2[i][rg] = -3e38f; bi[i][rg] = 0; }

    for (int t = 0; t < KC / 32; ++t) {
        __syncthreads();                      // prev tile's readers done
        #pragma unroll
        for (int i = 0; i < 4; ++i)
            *(us8*)(lds + (w * 4 + i) * 512 + l * 8) = st[i];
        __syncthreads();                      // tile t visible
        if (t < KC / 32 - 1) {
            #pragma unroll
            for (int i = 0; i < 4; ++i) st[i] = *(const us8*)(esrc[i] + (t + 1) * 32 * DIM);
        }
        const float h0 = hn[t * 32 + lr], h1 = hn[t * 32 + 16 + lr];
        f32x4 acc[2][2];
        #pragma unroll
        for (int i = 0; i < 2; ++i) {
            acc[i][0] = (f32x4){-h0, -h0, -h0, -h0};
            acc[i][1] = (f32x4){-h1, -h1, -h1, -h1};
        }
        #pragma unroll
        for (int kt = 0; kt < 4; ++kt) {
            bf16x8 bh0 = *(const bf16x8*)(lds + (0 + kt) * 512 + l * 8);
            bf16x8 bh1 = *(const bf16x8*)(lds + (4 + kt) * 512 + l * 8);
            bf16x8 bl0 = *(const bf16x8*)(lds + (8 + kt) * 512 + l * 8);
            bf16x8 bl1 = *(const bf16x8*)(lds + (12 + kt) * 512 + l * 8);
            #pragma unroll
            for (int i = 0; i < 2; ++i) {
                acc[i][0] = __builtin_amdgcn_mfma_f32_16x16x32_bf16(ah[i][kt], bh0, acc[i][0], 0, 0, 0);
                acc[i][0] = __builtin_amdgcn_mfma_f32_16x16x32_bf16(ah[i][kt], bl0, acc[i][0], 0, 0, 0);
                acc[i][0] = __builtin_amdgcn_mfma_f32_16x16x32_bf16(al[i][kt], bh0, acc[i][0], 0, 0, 0);
                acc[i][1] = __builtin_amdgcn_mfma_f32_16x16x32_bf16(ah[i][kt], bh1, acc[i][1], 0, 0, 0);
                acc[i][1] = __builtin_amdgcn_mfma_f32_16x16x32_bf16(ah[i][kt], bl1, acc[i][1], 0, 0, 0);
                acc[i][1] = __builtin_amdgcn_mfma_f32_16x16x32_bf16(al[i][kt], bh1, acc[i][1], 0, 0, 0);
            }
        }
        const int c0 = t * 32 + lr, c1 = c0 + 16;
        #pragma unroll
        for (int i = 0; i < 2; ++i)
            #pragma unroll
            for (int rg = 0; rg < 4; ++rg) {
                float v0 = acc[i][0][rg], v1 = acc[i][1][rg];
                if (v0 > m1[i][rg]) { m2[i][rg] = m1[i][rg]; m1[i][rg] = v0; bi[i][rg] = c0; }
                else if (v0 > m2[i][rg]) m2[i][rg] = v0;
                if (v1 > m1[i][rg]) { m2[i][rg] = m1[i][rg]; m1[i][rg] = v1; bi[i][rg] = c1; }
                else if (v1 > m2[i][rg]) m2[i][rg] = v1;
            }
    }

    // ---- merge top-2 across the 16 lanes sharing each row ----
    #pragma unroll
    for (int i = 0; i < 2; ++i)
        #pragma unroll
        for (int rg = 0; rg < 4; ++rg) {
            float a1 = m1[i][rg], a2 = m2[i][rg]; int ai = bi[i][rg];
            #pragma unroll
            for (int mask = 1; mask < 16; mask <<= 1) {
                float o1 = __shfl_xor(a1, mask);
                float o2 = __shfl_xor(a2, mask);
                int   oi = __shfl_xor(ai, mask);
                float nm2 = fmaxf(fmaxf(a2, o2), fminf(a1, o1));
                if (o1 > a1 || (o1 == a1 && oi < ai)) { a1 = o1; ai = oi; }
                a2 = nm2;
            }
            if (lr == 0) {
                int row = r0 + i * 16 + lg * 4 + rg;
                idx_out[row] = ai;
                if (a1 - a2 < GAP_THR) {      // near-tie: exact recheck later
                    int p = atomicAdd(flag_cnt, 1);
                    flagged[p] = row;
                }
            }
        }
}

// ---- exact fp64 recheck of near-tie rows (one wave per row) ----
__global__ void k_recheck(const float* __restrict__ x, const float* __restrict__ emb,
                          int* __restrict__ idx_out, const int* __restrict__ flag_cnt,
                          const int* __restrict__ flagged) {
    int gtid = blockIdx.x * blockDim.x + threadIdx.x;
    int wave = gtid >> 6;
    int lane = threadIdx.x & 63;
    int nw = (gridDim.x * blockDim.x) >> 6;
    int cnt = flag_cnt[0];
    for (int f = wave; f < cnt; f += nw) {
        int row = flagged[f];
        const float* xr = x + (size_t)row * DIM;
        double bestv = -1e300;
        int bestk = KC;
        for (int k = lane; k < KC; k += 64) {
            const float* ek = emb + (size_t)k * DIM;
            double s = 0.0, n2 = 0.0;
            for (int j = 0; j < DIM; ++j) {
                double e = ek[j], xv = xr[j];
                s = fma(e, xv, s);
                n2 = fma(e, e, n2);
            }
            s -= 0.5 * n2;
            if (s > bestv) { bestv = s; bestk = k; }
        }
        for (int off = 32; off; off >>= 1) {
            double ov = __shfl_down(bestv, off);
            int oi = __shfl_down(bestk, off);
            if (ov > bestv || (ov == bestv && oi < bestk)) { bestv = ov; bestk = oi; }
        }
        bestk = __shfl(bestk, 0);
        if (lane == 0) idx_out[row] = bestk;
    }
}

// ---- z, codes, diff partials, histogram ----
__global__ void k_output(const float* __restrict__ x, const float* __restrict__ emb,
                         const int* __restrict__ idx, float* __restrict__ out,
                         float* __restrict__ counts, float* __restrict__ dacc) {
    int t = blockIdx.x * blockDim.x + threadIdx.x;
    int e0 = t * 4;
    int row = e0 >> 7;
    int col = e0 & (DIM - 1);
    int k = idx[row];
    float4 xv = *(const float4*)(x + e0);
    float4 qv = *(const float4*)(emb + (size_t)k * DIM + col);
    float dx = qv.x - xv.x, dy = qv.y - xv.y, dz = qv.z - xv.z, dw = qv.w - xv.w;
    float4 z;
    z.x = xv.x + dx; z.y = xv.y + dy; z.z = xv.z + dz; z.w = xv.w + dw;
    *(float4*)(out + OUT_Z + e0) = z;
    float d = dx*dx + dy*dy + dz*dz + dw*dw;
    for (int off = 32; off; off >>= 1) d += __shfl_down(d, off);
    __shared__ float red[4];
    int lane = threadIdx.x & 63, w = threadIdx.x >> 6;
    if (lane == 0) red[w] = d;
    __syncthreads();
    if (threadIdx.x == 0) atomicAdd(dacc, (red[0] + red[1]) + (red[2] + red[3]));
    if (col == 0) {
        out[OUT_CODES + row] = (float)k;
        atomicAdd(&counts[k], 1.0f);
    }
}

// ---- diff mean + perplexity ----
__global__ void k_final(const float* __restrict__ counts, const float* __restrict__ dacc,
                        float* __restrict__ out) {
    __shared__ double sh[256];
    double local = 0.0;
    for (int k = threadIdx.x; k < KC; k += 256) {
        double p = (double)counts[k] * (1.0 / (double)NROWS);
        local += p * log(p + 1e-5);
    }
    sh[threadIdx.x] = local;
    __syncthreads();
    for (int s = 128; s; s >>= 1) {
        if (threadIdx.x < s) sh[threadIdx.x] += sh[threadIdx.x + s];
        __syncthreads();
    }
    if (threadIdx.x == 0) {
        out[OUT_DIFF] = dacc[0] * (1.0f / (float)XEL);
        out[OUT_PPL]  = (float)(-sh[0]);
    }
}

extern "C" void kernel_launch(void* const* d_in, const int* in_sizes, int n_in,
                              void* d_out, int out_size, void* d_ws, size_t ws_size,
                              hipStream_t stream) {
    const float* x   = (const float*)d_in[0];
    const float* emb = (const float*)d_in[1];
    float* out = (float*)d_out;
    int*   wi  = (int*)d_ws;
    float* wf  = (float*)d_ws;
    unsigned short* wus = (unsigned short*)d_ws;

    // zero: flag counter, histogram, diff accumulator (contiguous)
    hipMemsetAsync((char*)d_ws + (size_t)WS_CNT * 4, 0, (size_t)(2 + KC) * 4, stream);

    k_prep_e<<<(KC * DIM / 4) / 256, 256, 0, stream>>>(emb, wus + 2 * WS_EH, wus + 2 * WS_EL);
    k_halfnorm<<<(KC + 255) / 256, 256, 0, stream>>>(emb, wf + WS_HN);
    k_argmin<<<NROWS / 128, 256, 0, stream>>>(x, wus + 2 * WS_EH, wus + 2 * WS_EL,
                                              wf + WS_HN, wi + WS_IDX, wi + WS_CNT, wi + WS_FLAG);
    k_recheck<<<256, 256, 0, stream>>>(x, emb, wi + WS_IDX, wi + WS_CNT, wi + WS_FLAG);
    k_output<<<(XEL / 4) / 256, 256, 0, stream>>>(x, emb, wi + WS_IDX, out,
                                                  wf + WS_CNTS, wf + WS_DACC);
    k_final<<<1, 256, 0, stream>>>(wf + WS_CNTS, wf + WS_DACC, out);
}

// Round 3
// 185.830 us; speedup vs baseline: 7.7606x; 1.4940x over previous
//
#include <hip/hip_runtime.h>
#include <math.h>

constexpr int DIM   = 128;
constexpr int KC    = 1024;
constexpr int NROWS = 65536;                 // 16384*512/128
constexpr int XEL   = NROWS * DIM;           // 8388608

// output layout (floats)
constexpr int OUT_Z     = 0;
constexpr int OUT_DIFF  = XEL;               // 8388608
constexpr int OUT_CODES = XEL + 1;           // 8388609
constexpr int OUT_PPL   = XEL + 1 + NROWS;   // 8454145

// ws layout (4-byte units)
constexpr int WS_IDX  = 0;                   // int[NROWS]
constexpr int WS_FLAG = NROWS;               // int[NROWS]
constexpr int WS_CNT  = 2 * NROWS;           // int (zeroed)
constexpr int WS_HN   = WS_CNT + 1;          // float[KC]
constexpr int WS_PART = WS_HN + KC;          // float[2048] diff partials
constexpr int WS_EH   = WS_PART + 2048;      // ushort[KC*DIM] = 65536 words
constexpr int WS_EL   = WS_EH + (KC * DIM / 2);

constexpr int NB_OUT = 2048;                 // k_output blocks

constexpr float GAP_THR = 0.02f;             // score error ~5e-4; 40x margin

typedef __bf16 bf16x8 __attribute__((ext_vector_type(8)));
typedef unsigned short us8 __attribute__((ext_vector_type(8)));
typedef float f32x4 __attribute__((ext_vector_type(4)));

__device__ inline unsigned short f2bf(float f) {
    unsigned u = __builtin_bit_cast(unsigned, f);
    return (unsigned short)((u + 0x7FFFu + ((u >> 16) & 1u)) >> 16);
}
__device__ inline float bf2f(unsigned short h) {
    unsigned u = ((unsigned)h) << 16;
    return __builtin_bit_cast(float, u);
}

// ---- emb -> bf16 hi/lo splits ----
__global__ void k_prep_e(const float* __restrict__ emb, unsigned short* __restrict__ eh,
                         unsigned short* __restrict__ el) {
    int t = blockIdx.x * blockDim.x + threadIdx.x;
    int e0 = t * 4;
    float4 v = *(const float4*)(emb + e0);
    float vv[4] = {v.x, v.y, v.z, v.w};
    ushort4 h, lo;
    unsigned short* hp = &h.x; unsigned short* lp = &lo.x;
    #pragma unroll
    for (int j = 0; j < 4; ++j) {
        unsigned short hh = f2bf(vv[j]);
        hp[j] = hh;
        lp[j] = f2bf(vv[j] - bf2f(hh));
    }
    *(ushort4*)(eh + e0) = h;
    *(ushort4*)(el + e0) = lo;
}

// ---- half squared norms of codes, fp64-accurate then rounded once ----
__global__ void k_halfnorm(const float* __restrict__ emb, float* __restrict__ hn) {
    int k = blockIdx.x * blockDim.x + threadIdx.x;
    if (k >= KC) return;
    const float* e = emb + (size_t)k * DIM;
    double s = 0.0;
    for (int j = 0; j < DIM; ++j) { double v = e[j]; s = fma(v, v, s); }
    hn[k] = (float)(0.5 * s);
}

// ---- main: MFMA split-bf16 scores, per-row top-2 + argmax ----
__global__ __launch_bounds__(256) void k_argmin(
        const float* __restrict__ x,
        const unsigned short* __restrict__ eh, const unsigned short* __restrict__ el,
        const float* __restrict__ hn, int* __restrict__ idx_out,
        int* __restrict__ flag_cnt, int* __restrict__ flagged) {
    __shared__ unsigned short lds[8192];      // 16 KB: 16 chunks of 1 KB
    const int tid = threadIdx.x;
    const int l = tid & 63, w = tid >> 6;
    const int lr = l & 15, lg = l >> 4;       // row/col-select, k-group
    const int r0 = blockIdx.x * 128 + w * 32;

    // ---- A fragments: 32 rows, fp32 -> (hi,lo) bf16, kept in registers ----
    bf16x8 ah[2][4], al[2][4];
    #pragma unroll
    for (int i = 0; i < 2; ++i) {
        const float* xr = x + (size_t)(r0 + i * 16 + lr) * DIM + lg * 8;
        #pragma unroll
        for (int kt = 0; kt < 4; ++kt) {
            float4 v0 = *(const float4*)(xr + kt * 32);
            float4 v1 = *(const float4*)(xr + kt * 32 + 4);
            float vv[8] = {v0.x, v0.y, v0.z, v0.w, v1.x, v1.y, v1.z, v1.w};
            us8 h, lo;
            #pragma unroll
            for (int e = 0; e < 8; ++e) {
                unsigned short hh = f2bf(vv[e]);
                h[e] = hh;
                lo[e] = f2bf(vv[e] - bf2f(hh));
            }
            ah[i][kt] = __builtin_bit_cast(bf16x8, h);
            al[i][kt] = __builtin_bit_cast(bf16x8, lo);
        }
    }

    // staging source pointers: chunk q = w*4+i; split=q>>3, cf=(q>>2)&1, kt=q&3
    const unsigned short* esrc[4];
    #pragma unroll
    for (int i = 0; i < 4; ++i) {
        int q = w * 4 + i;
        const unsigned short* base = (q >> 3) ? el : eh;
        esrc[i] = base + (((q >> 2) & 1) * 16 + lr) * DIM + (q & 3) * 32 + lg * 8;
    }
    us8 st[4];
    #pragma unroll
    for (int i = 0; i < 4; ++i) st[i] = *(const us8*)(esrc[i]);

    float m1[2][4], m2[2][4]; int bi[2][4];
    #pragma unroll
    for (int i = 0; i < 2; ++i)
        #pragma unroll
        for (int rg = 0; rg < 4; ++rg) { m1[i][rg] = -3e38f; m2[i][rg] = -3e38f; bi[i][rg] = 0; }

    for (int t = 0; t < KC / 32; ++t) {
        __syncthreads();                      // prev tile's readers done
        #pragma unroll
        for (int i = 0; i < 4; ++i)
            *(us8*)(lds + (w * 4 + i) * 512 + l * 8) = st[i];
        __syncthreads();                      // tile t visible
        if (t < KC / 32 - 1) {
            #pragma unroll
            for (int i = 0; i < 4; ++i) st[i] = *(const us8*)(esrc[i] + (t + 1) * 32 * DIM);
        }
        const float h0 = hn[t * 32 + lr], h1 = hn[t * 32 + 16 + lr];
        f32x4 acc[2][2];
        #pragma unroll
        for (int i = 0; i < 2; ++i) {
            acc[i][0] = (f32x4){-h0, -h0, -h0, -h0};
            acc[i][1] = (f32x4){-h1, -h1, -h1, -h1};
        }
        #pragma unroll
        for (int kt = 0; kt < 4; ++kt) {
            bf16x8 bh0 = *(const bf16x8*)(lds + (0 + kt) * 512 + l * 8);
            bf16x8 bh1 = *(const bf16x8*)(lds + (4 + kt) * 512 + l * 8);
            bf16x8 bl0 = *(const bf16x8*)(lds + (8 + kt) * 512 + l * 8);
            bf16x8 bl1 = *(const bf16x8*)(lds + (12 + kt) * 512 + l * 8);
            #pragma unroll
            for (int i = 0; i < 2; ++i) {
                acc[i][0] = __builtin_amdgcn_mfma_f32_16x16x32_bf16(ah[i][kt], bh0, acc[i][0], 0, 0, 0);
                acc[i][0] = __builtin_amdgcn_mfma_f32_16x16x32_bf16(ah[i][kt], bl0, acc[i][0], 0, 0, 0);
                acc[i][0] = __builtin_amdgcn_mfma_f32_16x16x32_bf16(al[i][kt], bh0, acc[i][0], 0, 0, 0);
                acc[i][1] = __builtin_amdgcn_mfma_f32_16x16x32_bf16(ah[i][kt], bh1, acc[i][1], 0, 0, 0);
                acc[i][1] = __builtin_amdgcn_mfma_f32_16x16x32_bf16(ah[i][kt], bl1, acc[i][1], 0, 0, 0);
                acc[i][1] = __builtin_amdgcn_mfma_f32_16x16x32_bf16(al[i][kt], bh1, acc[i][1], 0, 0, 0);
            }
        }
        const int c0 = t * 32 + lr, c1 = c0 + 16;
        #pragma unroll
        for (int i = 0; i < 2; ++i)
            #pragma unroll
            for (int rg = 0; rg < 4; ++rg) {
                // branch-free top-2: m2' = med3(v,m1,m2), m1' = max, idx select
                float v0 = acc[i][0][rg], v1 = acc[i][1][rg];
                bool g0 = v0 > m1[i][rg];
                m2[i][rg] = fmaxf(m2[i][rg], fminf(v0, m1[i][rg]));
                m1[i][rg] = fmaxf(m1[i][rg], v0);
                bi[i][rg] = g0 ? c0 : bi[i][rg];
                bool g1 = v1 > m1[i][rg];
                m2[i][rg] = fmaxf(m2[i][rg], fminf(v1, m1[i][rg]));
                m1[i][rg] = fmaxf(m1[i][rg], v1);
                bi[i][rg] = g1 ? c1 : bi[i][rg];
            }
    }

    // ---- merge top-2 across the 16 lanes sharing each row ----
    #pragma unroll
    for (int i = 0; i < 2; ++i)
        #pragma unroll
        for (int rg = 0; rg < 4; ++rg) {
            float a1 = m1[i][rg], a2 = m2[i][rg]; int ai = bi[i][rg];
            #pragma unroll
            for (int mask = 1; mask < 16; mask <<= 1) {
                float o1 = __shfl_xor(a1, mask);
                float o2 = __shfl_xor(a2, mask);
                int   oi = __shfl_xor(ai, mask);
                float nm2 = fmaxf(fmaxf(a2, o2), fminf(a1, o1));
                if (o1 > a1 || (o1 == a1 && oi < ai)) { a1 = o1; ai = oi; }
                a2 = nm2;
            }
            if (lr == 0) {
                int row = r0 + i * 16 + lg * 4 + rg;
                idx_out[row] = ai;
                if (a1 - a2 < GAP_THR) {      // near-tie: exact recheck later
                    int p = atomicAdd(flag_cnt, 1);
                    flagged[p] = row;
                }
            }
        }
}

// ---- exact fp64 recheck of near-tie rows (one wave per row) ----
__global__ void k_recheck(const float* __restrict__ x, const float* __restrict__ emb,
                          int* __restrict__ idx_out, const int* __restrict__ flag_cnt,
                          const int* __restrict__ flagged) {
    int gtid = blockIdx.x * blockDim.x + threadIdx.x;
    int wave = gtid >> 6;
    int lane = threadIdx.x & 63;
    int nw = (gridDim.x * blockDim.x) >> 6;
    int cnt = flag_cnt[0];
    for (int f = wave; f < cnt; f += nw) {
        int row = flagged[f];
        const float* xr = x + (size_t)row * DIM;
        double bestv = -1e300;
        int bestk = KC;
        for (int k = lane; k < KC; k += 64) {
            const float* ek = emb + (size_t)k * DIM;
            double s = 0.0, n2 = 0.0;
            for (int j = 0; j < DIM; ++j) {
                double e = ek[j], xv = xr[j];
                s = fma(e, xv, s);
                n2 = fma(e, e, n2);
            }
            s -= 0.5 * n2;
            if (s > bestv) { bestv = s; bestk = k; }
        }
        for (int off = 32; off; off >>= 1) {
            double ov = __shfl_down(bestv, off);
            int oi = __shfl_down(bestk, off);
            if (ov > bestv || (ov == bestv && oi < bestk)) { bestv = ov; bestk = oi; }
        }
        bestk = __shfl(bestk, 0);
        if (lane == 0) idx_out[row] = bestk;
    }
}

// ---- z, codes, diff partials (NO global atomics) ----
__global__ __launch_bounds__(256) void k_output(
        const float* __restrict__ x, const float* __restrict__ emb,
        const int* __restrict__ idx, float* __restrict__ out,
        float* __restrict__ part) {
    const int tid = threadIdx.x;
    float d = 0.f;
    #pragma unroll
    for (int it = 0; it < 4; ++it) {
        int i = blockIdx.x * 256 + tid + it * (NB_OUT * 256);
        int e0 = i * 4;
        int row = e0 >> 7;
        int col = e0 & (DIM - 1);
        int k = idx[row];
        float4 xv = *(const float4*)(x + e0);
        float4 qv = *(const float4*)(emb + (size_t)k * DIM + col);
        float dx = qv.x - xv.x, dy = qv.y - xv.y, dz = qv.z - xv.z, dw = qv.w - xv.w;
        float4 z;
        z.x = xv.x + dx; z.y = xv.y + dy; z.z = xv.z + dz; z.w = xv.w + dw;
        *(float4*)(out + OUT_Z + e0) = z;
        d += dx*dx + dy*dy + dz*dz + dw*dw;
        if (col == 0) out[OUT_CODES + row] = (float)k;
    }
    // wave reduce then block partial -> plain store (no atomics)
    for (int off = 32; off; off >>= 1) d += __shfl_down(d, off);
    __shared__ float red[4];
    int lane = tid & 63, w = tid >> 6;
    if (lane == 0) red[w] = d;
    __syncthreads();
    if (tid == 0) part[blockIdx.x] = (red[0] + red[1]) + (red[2] + red[3]);
}

// ---- single block: LDS histogram + perplexity + diff mean ----
__global__ __launch_bounds__(1024) void k_final(
        const int* __restrict__ idx, const float* __restrict__ part,
        float* __restrict__ out) {
    __shared__ unsigned hist[KC];
    __shared__ double sh[1024];
    const int tid = threadIdx.x;
    if (tid < KC) hist[tid] = 0u;
    __syncthreads();
    #pragma unroll
    for (int it = 0; it < NROWS / 1024; ++it)
        atomicAdd(&hist[idx[it * 1024 + tid]], 1u);
    // diff partial sum (fp64)
    double ds = (double)part[tid] + (double)part[tid + 1024];
    sh[tid] = ds;
    __syncthreads();
    for (int s = 512; s; s >>= 1) {
        if (tid < s) sh[tid] += sh[tid + s];
        __syncthreads();
    }
    double diff = sh[0] * (1.0 / (double)XEL);
    // perplexity term per bin
    double local = 0.0;
    if (tid < KC) {
        double p = (double)hist[tid] * (1.0 / (double)NROWS);
        local = p * log(p + 1e-5);
    }
    __syncthreads();
    sh[tid] = local;
    __syncthreads();
    for (int s = 512; s; s >>= 1) {
        if (tid < s) sh[tid] += sh[tid + s];
        __syncthreads();
    }
    if (tid == 0) {
        out[OUT_DIFF] = (float)diff;
        out[OUT_PPL]  = (float)(-sh[0]);
    }
}

extern "C" void kernel_launch(void* const* d_in, const int* in_sizes, int n_in,
                              void* d_out, int out_size, void* d_ws, size_t ws_size,
                              hipStream_t stream) {
    const float* x   = (const float*)d_in[0];
    const float* emb = (const float*)d_in[1];
    float* out = (float*)d_out;
    int*   wi  = (int*)d_ws;
    float* wf  = (float*)d_ws;
    unsigned short* wus = (unsigned short*)d_ws;

    hipMemsetAsync((char*)d_ws + (size_t)WS_CNT * 4, 0, 4, stream);  // flag counter

    k_prep_e<<<(KC * DIM / 4) / 256, 256, 0, stream>>>(emb, wus + 2 * WS_EH, wus + 2 * WS_EL);
    k_halfnorm<<<(KC + 255) / 256, 256, 0, stream>>>(emb, wf + WS_HN);
    k_argmin<<<NROWS / 128, 256, 0, stream>>>(x, wus + 2 * WS_EH, wus + 2 * WS_EL,
                                              wf + WS_HN, wi + WS_IDX, wi + WS_CNT, wi + WS_FLAG);
    k_recheck<<<256, 256, 0, stream>>>(x, emb, wi + WS_IDX, wi + WS_CNT, wi + WS_FLAG);
    k_output<<<NB_OUT, 256, 0, stream>>>(x, emb, wi + WS_IDX, out, wf + WS_PART);
    k_final<<<1, 1024, 0, stream>>>(wi + WS_IDX, wf + WS_PART, out);
}

// Round 4
// 126.873 us; speedup vs baseline: 11.3669x; 1.4647x over previous
//
#include <hip/hip_runtime.h>
#include <math.h>

constexpr int DIM   = 128;
constexpr int KC    = 1024;
constexpr int NROWS = 65536;                 // 16384*512/128
constexpr int XEL   = NROWS * DIM;           // 8388608

// output layout (floats)
constexpr int OUT_Z     = 0;
constexpr int OUT_DIFF  = XEL;               // 8388608
constexpr int OUT_CODES = XEL + 1;           // 8388609
constexpr int OUT_PPL   = XEL + 1 + NROWS;   // 8454145

// ws layout (4-byte units)
constexpr int WS_IDX  = 0;                   // int[NROWS]
constexpr int WS_FLAG = NROWS;               // int[NROWS]
constexpr int WS_CNT  = 2 * NROWS;           // int (zeroed)
constexpr int WS_HIST = WS_CNT + 1;          // u32[KC] (zeroed)
constexpr int WS_HN   = WS_HIST + KC;        // float[KC]
constexpr int WS_PART = WS_HN + KC;          // float[2048] diff partials
constexpr int WS_EH   = WS_PART + 2048;      // ushort[KC*DIM] = 65536 words
constexpr int WS_EL   = WS_EH + (KC * DIM / 2);

constexpr int NB_OUT = 2048;                 // k_output blocks

constexpr float GAP_THR = 0.02f;             // score error ~2e-4; 100x margin

typedef __bf16 bf16x8 __attribute__((ext_vector_type(8)));
typedef unsigned short us8 __attribute__((ext_vector_type(8)));
typedef float f32x4 __attribute__((ext_vector_type(4)));

__device__ inline unsigned short f2bf(float f) {
    unsigned u = __builtin_bit_cast(unsigned, f);
    return (unsigned short)((u + 0x7FFFu + ((u >> 16) & 1u)) >> 16);
}
__device__ inline float bf2f(unsigned short h) {
    unsigned u = ((unsigned)h) << 16;
    return __builtin_bit_cast(float, u);
}

// ---- emb -> bf16 hi/lo splits ----
__global__ void k_prep_e(const float* __restrict__ emb, unsigned short* __restrict__ eh,
                         unsigned short* __restrict__ el) {
    int t = blockIdx.x * blockDim.x + threadIdx.x;
    int e0 = t * 4;
    float4 v = *(const float4*)(emb + e0);
    float vv[4] = {v.x, v.y, v.z, v.w};
    ushort4 h, lo;
    unsigned short* hp = &h.x; unsigned short* lp = &lo.x;
    #pragma unroll
    for (int j = 0; j < 4; ++j) {
        unsigned short hh = f2bf(vv[j]);
        hp[j] = hh;
        lp[j] = f2bf(vv[j] - bf2f(hh));
    }
    *(ushort4*)(eh + e0) = h;
    *(ushort4*)(el + e0) = lo;
}

// ---- half squared norms of codes, fp64-accurate then rounded once ----
__global__ void k_halfnorm(const float* __restrict__ emb, float* __restrict__ hn) {
    int k = blockIdx.x * blockDim.x + threadIdx.x;
    if (k >= KC) return;
    const float* e = emb + (size_t)k * DIM;
    double s = 0.0;
    for (int j = 0; j < DIM; ++j) { double v = e[j]; s = fma(v, v, s); }
    hn[k] = (float)(0.5 * s);
}

// ---- main: MFMA split-bf16 scores, per-row top-2 + argmax ----
__global__ __launch_bounds__(256) void k_argmin(
        const float* __restrict__ x,
        const unsigned short* __restrict__ eh, const unsigned short* __restrict__ el,
        const float* __restrict__ hn, int* __restrict__ idx_out,
        int* __restrict__ flag_cnt, int* __restrict__ flagged) {
    __shared__ unsigned short lds[8192];      // 16 KB: 16 chunks of 1 KB
    const int tid = threadIdx.x;
    const int l = tid & 63, w = tid >> 6;
    const int lr = l & 15, lg = l >> 4;       // row/col-select, k-group
    const int r0 = blockIdx.x * 128 + w * 32;

    // ---- A fragments: 32 rows, fp32 -> (hi,lo) bf16, kept in registers ----
    bf16x8 ah[2][4], al[2][4];
    #pragma unroll
    for (int i = 0; i < 2; ++i) {
        const float* xr = x + (size_t)(r0 + i * 16 + lr) * DIM + lg * 8;
        #pragma unroll
        for (int kt = 0; kt < 4; ++kt) {
            float4 v0 = *(const float4*)(xr + kt * 32);
            float4 v1 = *(const float4*)(xr + kt * 32 + 4);
            float vv[8] = {v0.x, v0.y, v0.z, v0.w, v1.x, v1.y, v1.z, v1.w};
            us8 h, lo;
            #pragma unroll
            for (int e = 0; e < 8; ++e) {
                unsigned short hh = f2bf(vv[e]);
                h[e] = hh;
                lo[e] = f2bf(vv[e] - bf2f(hh));
            }
            ah[i][kt] = __builtin_bit_cast(bf16x8, h);
            al[i][kt] = __builtin_bit_cast(bf16x8, lo);
        }
    }

    // staging source pointers: chunk q = w*4+i; split=q>>3, cf=(q>>2)&1, kt=q&3
    const unsigned short* esrc[4];
    #pragma unroll
    for (int i = 0; i < 4; ++i) {
        int q = w * 4 + i;
        const unsigned short* base = (q >> 3) ? el : eh;
        esrc[i] = base + (((q >> 2) & 1) * 16 + lr) * DIM + (q & 3) * 32 + lg * 8;
    }
    us8 st[4];
    #pragma unroll
    for (int i = 0; i < 4; ++i) st[i] = *(const us8*)(esrc[i]);

    float m1[2][4], m2[2][4]; int bi[2][4];
    #pragma unroll
    for (int i = 0; i < 2; ++i)
        #pragma unroll
        for (int rg = 0; rg < 4; ++rg) { m1[i][rg] = -3e38f; m2[i][rg] = -3e38f; bi[i][rg] = 0; }

    for (int t = 0; t < KC / 32; ++t) {
        __syncthreads();                      // prev tile's readers done
        #pragma unroll
        for (int i = 0; i < 4; ++i)
            *(us8*)(lds + (w * 4 + i) * 512 + l * 8) = st[i];
        __syncthreads();                      // tile t visible
        if (t < KC / 32 - 1) {
            #pragma unroll
            for (int i = 0; i < 4; ++i) st[i] = *(const us8*)(esrc[i] + (t + 1) * 32 * DIM);
        }
        const float h0 = hn[t * 32 + lr], h1 = hn[t * 32 + 16 + lr];
        f32x4 acc[2][2];
        #pragma unroll
        for (int i = 0; i < 2; ++i) {
            acc[i][0] = (f32x4){-h0, -h0, -h0, -h0};
            acc[i][1] = (f32x4){-h1, -h1, -h1, -h1};
        }
        #pragma unroll
        for (int kt = 0; kt < 4; ++kt) {
            bf16x8 bh0 = *(const bf16x8*)(lds + (0 + kt) * 512 + l * 8);
            bf16x8 bh1 = *(const bf16x8*)(lds + (4 + kt) * 512 + l * 8);
            bf16x8 bl0 = *(const bf16x8*)(lds + (8 + kt) * 512 + l * 8);
            bf16x8 bl1 = *(const bf16x8*)(lds + (12 + kt) * 512 + l * 8);
            #pragma unroll
            for (int i = 0; i < 2; ++i) {
                acc[i][0] = __builtin_amdgcn_mfma_f32_16x16x32_bf16(ah[i][kt], bh0, acc[i][0], 0, 0, 0);
                acc[i][0] = __builtin_amdgcn_mfma_f32_16x16x32_bf16(ah[i][kt], bl0, acc[i][0], 0, 0, 0);
                acc[i][0] = __builtin_amdgcn_mfma_f32_16x16x32_bf16(al[i][kt], bh0, acc[i][0], 0, 0, 0);
                acc[i][1] = __builtin_amdgcn_mfma_f32_16x16x32_bf16(ah[i][kt], bh1, acc[i][1], 0, 0, 0);
                acc[i][1] = __builtin_amdgcn_mfma_f32_16x16x32_bf16(ah[i][kt], bl1, acc[i][1], 0, 0, 0);
                acc[i][1] = __builtin_amdgcn_mfma_f32_16x16x32_bf16(al[i][kt], bh1, acc[i][1], 0, 0, 0);
            }
        }
        const int c0 = t * 32 + lr, c1 = c0 + 16;
        #pragma unroll
        for (int i = 0; i < 2; ++i)
            #pragma unroll
            for (int rg = 0; rg < 4; ++rg) {
                float v0 = acc[i][0][rg], v1 = acc[i][1][rg];
                bool g0 = v0 > m1[i][rg];
                m2[i][rg] = fmaxf(m2[i][rg], fminf(v0, m1[i][rg]));
                m1[i][rg] = fmaxf(m1[i][rg], v0);
                bi[i][rg] = g0 ? c0 : bi[i][rg];
                bool g1 = v1 > m1[i][rg];
                m2[i][rg] = fmaxf(m2[i][rg], fminf(v1, m1[i][rg]));
                m1[i][rg] = fmaxf(m1[i][rg], v1);
                bi[i][rg] = g1 ? c1 : bi[i][rg];
            }
    }

    // ---- merge top-2 across the 16 lanes sharing each row ----
    #pragma unroll
    for (int i = 0; i < 2; ++i)
        #pragma unroll
        for (int rg = 0; rg < 4; ++rg) {
            float a1 = m1[i][rg], a2 = m2[i][rg]; int ai = bi[i][rg];
            #pragma unroll
            for (int mask = 1; mask < 16; mask <<= 1) {
                float o1 = __shfl_xor(a1, mask);
                float o2 = __shfl_xor(a2, mask);
                int   oi = __shfl_xor(ai, mask);
                float nm2 = fmaxf(fmaxf(a2, o2), fminf(a1, o1));
                if (o1 > a1 || (o1 == a1 && oi < ai)) { a1 = o1; ai = oi; }
                a2 = nm2;
            }
            if (lr == 0) {
                int row = r0 + i * 16 + lg * 4 + rg;
                idx_out[row] = ai;
                if (a1 - a2 < GAP_THR) {      // near-tie: exact recheck later
                    int p = atomicAdd(flag_cnt, 1);
                    flagged[p] = row;
                }
            }
        }
}

// ---- exact fp64 recheck: one block per flagged row, thread per code ----
__global__ __launch_bounds__(256) void k_recheck(
        const float* __restrict__ x, const float* __restrict__ emb,
        int* __restrict__ idx_out, const int* __restrict__ flag_cnt,
        const int* __restrict__ flagged) {
    __shared__ float xs[DIM];
    __shared__ double wv[4];
    __shared__ int    wk[4];
    const int tid = threadIdx.x;
    const int cnt = flag_cnt[0];
    for (int f = blockIdx.x; f < cnt; f += gridDim.x) {
        const int row = flagged[f];
        __syncthreads();                       // xs/wv reuse guard
        if (tid < DIM) xs[tid] = x[(size_t)row * DIM + tid];
        __syncthreads();
        double bv = -1e300; int bk = 0;
        #pragma unroll
        for (int tile = 0; tile < 4; ++tile) {
            const int k = tile * 256 + tid;
            const float4* ep = (const float4*)(emb + (size_t)k * DIM);
            const float4* xp = (const float4*)xs;
            double s = 0.0, n2 = 0.0;
            #pragma unroll 8
            for (int jq = 0; jq < DIM / 4; ++jq) {
                float4 ev = ep[jq];
                float4 xv = xp[jq];
                double e0 = ev.x, e1 = ev.y, e2 = ev.z, e3 = ev.w;
                s  = fma(e0, (double)xv.x, s);  n2 = fma(e0, e0, n2);
                s  = fma(e1, (double)xv.y, s);  n2 = fma(e1, e1, n2);
                s  = fma(e2, (double)xv.z, s);  n2 = fma(e2, e2, n2);
                s  = fma(e3, (double)xv.w, s);  n2 = fma(e3, e3, n2);
            }
            s -= 0.5 * n2;
            if (s > bv) { bv = s; bk = k; }   // ascending k keeps first-min
        }
        #pragma unroll
        for (int m = 1; m < 64; m <<= 1) {
            double ov = __shfl_xor(bv, m);
            int    ok = __shfl_xor(bk, m);
            if (ov > bv || (ov == bv && ok < bk)) { bv = ov; bk = ok; }
        }
        const int w = tid >> 6;
        if ((tid & 63) == 0) { wv[w] = bv; wk[w] = bk; }
        __syncthreads();
        if (tid == 0) {
            double fv = wv[0]; int fk = wk[0];
            #pragma unroll
            for (int i = 1; i < 4; ++i)
                if (wv[i] > fv || (wv[i] == fv && wk[i] < fk)) { fv = wv[i]; fk = wk[i]; }
            idx_out[row] = fk;
        }
    }
}

// ---- z, codes, diff partials (NO global atomics) ----
__global__ __launch_bounds__(256) void k_output(
        const float* __restrict__ x, const float* __restrict__ emb,
        const int* __restrict__ idx, float* __restrict__ out,
        float* __restrict__ part) {
    const int tid = threadIdx.x;
    float d = 0.f;
    #pragma unroll
    for (int it = 0; it < 4; ++it) {
        int i = blockIdx.x * 256 + tid + it * (NB_OUT * 256);
        int e0 = i * 4;
        int row = e0 >> 7;
        int col = e0 & (DIM - 1);
        int k = idx[row];
        float4 xv = *(const float4*)(x + e0);
        float4 qv = *(const float4*)(emb + (size_t)k * DIM + col);
        float dx = qv.x - xv.x, dy = qv.y - xv.y, dz = qv.z - xv.z, dw = qv.w - xv.w;
        float4 z;
        z.x = xv.x + dx; z.y = xv.y + dy; z.z = xv.z + dz; z.w = xv.w + dw;
        *(float4*)(out + OUT_Z + e0) = z;
        d += dx*dx + dy*dy + dz*dz + dw*dw;
        if (col == 0) out[OUT_CODES + row] = (float)k;
    }
    for (int off = 32; off; off >>= 1) d += __shfl_down(d, off);
    __shared__ float red[4];
    int lane = tid & 63, w = tid >> 6;
    if (lane == 0) red[w] = d;
    __syncthreads();
    if (tid == 0) part[blockIdx.x] = (red[0] + red[1]) + (red[2] + red[3]);
}

// ---- histogram: 64 blocks, LDS hist then global-atomic merge ----
__global__ __launch_bounds__(256) void k_hist(
        const int* __restrict__ idx, unsigned* __restrict__ ghist) {
    __shared__ unsigned hist[KC];
    const int tid = threadIdx.x;
    #pragma unroll
    for (int i = 0; i < KC / 256; ++i) hist[i * 256 + tid] = 0u;
    __syncthreads();
    const int base = blockIdx.x * (NROWS / 64);
    #pragma unroll
    for (int it = 0; it < NROWS / 64 / 256; ++it)
        atomicAdd(&hist[idx[base + it * 256 + tid]], 1u);
    __syncthreads();
    #pragma unroll
    for (int i = 0; i < KC / 256; ++i) {
        unsigned c = hist[i * 256 + tid];
        if (c) atomicAdd(&ghist[i * 256 + tid], c);
    }
}

// ---- diff mean + perplexity ----
__global__ __launch_bounds__(1024) void k_final(
        const unsigned* __restrict__ ghist, const float* __restrict__ part,
        float* __restrict__ out) {
    __shared__ double sh[1024];
    const int tid = threadIdx.x;
    sh[tid] = (double)part[tid] + (double)part[tid + 1024];
    __syncthreads();
    for (int s = 512; s; s >>= 1) {
        if (tid < s) sh[tid] += sh[tid + s];
        __syncthreads();
    }
    double diff = sh[0] * (1.0 / (double)XEL);
    double local = 0.0;
    if (tid < KC) {
        double p = (double)ghist[tid] * (1.0 / (double)NROWS);
        local = p * log(p + 1e-5);
    }
    __syncthreads();
    sh[tid] = local;
    __syncthreads();
    for (int s = 512; s; s >>= 1) {
        if (tid < s) sh[tid] += sh[tid + s];
        __syncthreads();
    }
    if (tid == 0) {
        out[OUT_DIFF] = (float)diff;
        out[OUT_PPL]  = (float)(-sh[0]);
    }
}

extern "C" void kernel_launch(void* const* d_in, const int* in_sizes, int n_in,
                              void* d_out, int out_size, void* d_ws, size_t ws_size,
                              hipStream_t stream) {
    const float* x   = (const float*)d_in[0];
    const float* emb = (const float*)d_in[1];
    float* out = (float*)d_out;
    int*   wi  = (int*)d_ws;
    float* wf  = (float*)d_ws;
    unsigned* wu = (unsigned*)d_ws;
    unsigned short* wus = (unsigned short*)d_ws;

    // zero: flag counter + global histogram (contiguous)
    hipMemsetAsync((char*)d_ws + (size_t)WS_CNT * 4, 0, (size_t)(1 + KC) * 4, stream);

    k_prep_e<<<(KC * DIM / 4) / 256, 256, 0, stream>>>(emb, wus + 2 * WS_EH, wus + 2 * WS_EL);
    k_halfnorm<<<(KC + 255) / 256, 256, 0, stream>>>(emb, wf + WS_HN);
    k_argmin<<<NROWS / 128, 256, 0, stream>>>(x, wus + 2 * WS_EH, wus + 2 * WS_EL,
                                              wf + WS_HN, wi + WS_IDX, wi + WS_CNT, wi + WS_FLAG);
    k_recheck<<<512, 256, 0, stream>>>(x, emb, wi + WS_IDX, wi + WS_CNT, wi + WS_FLAG);
    k_output<<<NB_OUT, 256, 0, stream>>>(x, emb, wi + WS_IDX, out, wf + WS_PART);
    k_hist<<<64, 256, 0, stream>>>(wi + WS_IDX, wu + WS_HIST);
    k_final<<<1, 1024, 0, stream>>>(wu + WS_HIST, wf + WS_PART, out);
}